// Round 6
// baseline (759.443 us; speedup 1.0000x reference)
//
#include <hip/hip_runtime.h>
#include <hip/hip_bf16.h>

// FiLM + 2-layer preact resnet, fully fused. N=65536, H=256, C=512.
// Round 6: K-quarter cond staging overlapped with GEMM1 (loads issued before
// MFMA, ds_write in 2-barrier windows), x staged chunk-wise inside the same
// windows, residual in registers, 48KB LDS -> 3 blocks/CU, setprio on MFMA.

typedef __attribute__((ext_vector_type(8))) short bf16x8;   // 8 bf16 = 4 VGPR
typedef __attribute__((ext_vector_type(4))) float f32x4;    // MFMA C/D

typedef unsigned short ushort_t;
typedef unsigned int uint_t;

__device__ __forceinline__ ushort_t f2bf(float f) {
  union { float f; uint_t u; } v; v.f = f;
  uint_t u = v.u;
  return (ushort_t)((u + 0x7FFFu + ((u >> 16) & 1u)) >> 16);  // RNE
}
__device__ __forceinline__ float bf2f(ushort_t s) {
  union { uint_t u; float f; } v; v.u = ((uint_t)s) << 16;
  return v.f;
}
__device__ __forceinline__ bf16x8 ldfrag(const ushort_t* p) {
  return *reinterpret_cast<const bf16x8*>(p);
}
__device__ __forceinline__ bf16x8 pack8(float4 a, float4 b) {
  union { bf16x8 v; ushort_t s[8]; } h;
  h.s[0]=f2bf(a.x); h.s[1]=f2bf(a.y); h.s[2]=f2bf(a.z); h.s[3]=f2bf(a.w);
  h.s[4]=f2bf(b.x); h.s[5]=f2bf(b.y); h.s[6]=f2bf(b.z); h.s[7]=f2bf(b.w);
  return h.v;
}

// ---------------------------------------------------------------------------
// Pack weights (fp32 row-major [K][Ncols]) into bf16 MFMA-B fragment order:
//   p[((nt*KT + kt)*64 + lane)*8 + j] = W[kt*32 + (lane>>4)*8 + j][nt*16 + (lane&15)]
// ---------------------------------------------------------------------------
__global__ void pack_weights(const float* __restrict__ Wf,
                             const float* __restrict__ W1,
                             const float* __restrict__ W2,
                             ushort_t* __restrict__ p1,
                             ushort_t* __restrict__ pW1,
                             ushort_t* __restrict__ pW2) {
  int u = blockIdx.x * 256 + threadIdx.x;
  if (u < 32768) {
    int lane = u & 63, rest = u >> 6;
    int kt = rest & 15;
    int kb = kt * 32 + (lane >> 4) * 8;
    int col = (rest >> 4) * 16 + (lane & 15);
#pragma unroll
    for (int j = 0; j < 8; ++j)
      p1[(size_t)u * 8 + j] = f2bf(Wf[(size_t)(kb + j) * 512 + col]);
  } else if (u < 40960) {
    int v = u - 32768;
    int lane = v & 63;
    int kt = (v >> 6) & 7;
    int kb = kt * 32 + (lane >> 4) * 8;
    int col = (v >> 9) * 16 + (lane & 15);
#pragma unroll
    for (int j = 0; j < 8; ++j)
      pW1[(size_t)v * 8 + j] = f2bf(W1[(size_t)(kb + j) * 256 + col]);
  } else if (u < 49152) {
    int v = u - 40960;
    int lane = v & 63;
    int kt = (v >> 6) & 7;
    int kb = kt * 32 + (lane >> 4) * 8;
    int col = (v >> 9) * 16 + (lane & 15);
#pragma unroll
    for (int j = 0; j < 8; ++j)
      pW2[(size_t)v * 8 + j] = f2bf(W2[(size_t)(kb + j) * 256 + col]);
  }
}

// ---------------------------------------------------------------------------
// 1 workgroup = 64 rows, 4 waves; wave w owns output cols [w*64, w*64+64).
// LDS 48KB:
//   condq = lds[0,16K):   cond K-quarter bf16 [64][128] swz (single buffer,
//                         restaged per quarter in a 2-barrier window)
//   B     = lds[16K,48K): x bf16 [64][256] swz -> r1 -> r2 -> epi fp32 [32][256]
// XOR swizzle: byte ^= (row&15)<<4.
// ---------------------------------------------------------------------------
__global__ __launch_bounds__(256, 3)
void film_fused(const float* __restrict__ x, const float* __restrict__ cond,
                const float* __restrict__ b_film, const float* __restrict__ b1,
                const float* __restrict__ b2,
                const ushort_t* __restrict__ p1, const ushort_t* __restrict__ pW1,
                const ushort_t* __restrict__ pW2, float* __restrict__ out) {
  __shared__ __align__(16) char lds[49152];
  char* condq = lds;              // 16KB
  char* B = lds + 16384;          // 32KB
  const int r0 = blockIdx.x * 64;
  const int t = threadIdx.x;
  const int w = t >> 6;
  const int l = t & 63;
  const int l15 = l & 15;
  const int lhi = l >> 4;

  // ---- per-lane bias preloads (tiny, L2-hot)
  float bgv[4], bbv[4], b1v[4], b2v[4];
#pragma unroll
  for (int tt = 0; tt < 4; ++tt) {
    int colg = w * 64 + tt * 16 + l15;
    bgv[tt] = b_film[colg];
    bbv[tt] = b_film[256 + colg];
    b1v[tt] = b1[colg];
    b2v[tt] = b2[colg];
  }

  // ---- initial stage: cond quarter 0 ([64][128] fp32 -> bf16 LDS)
  // mapping: pair p in 0..3, j in 0..1: g = p*512 + t*2 + j (f4 index)
  //   row = g>>5, colf = (g&31)*4   (8 consecutive floats per (p) pair)
  {
    float4 c0[8];
#pragma unroll
    for (int p = 0; p < 4; ++p)
#pragma unroll
      for (int j = 0; j < 2; ++j) {
        int g = p * 512 + t * 2 + j;
        c0[p * 2 + j] = *reinterpret_cast<const float4*>(
            cond + (size_t)(r0 + (g >> 5)) * 512 + (g & 31) * 4);
      }
    // GEMM1 B preload (ktg=0) before the barrier
#pragma unroll
    for (int p = 0; p < 4; ++p) {
      int g = p * 512 + t * 2;
      int row = g >> 5, colf = (g & 31) * 4;
      int byte = row * 256 + colf * 2;
      byte ^= ((row & 15) << 4);
      *reinterpret_cast<bf16x8*>(condq + byte) = pack8(c0[p * 2], c0[p * 2 + 1]);
    }
  }
  bf16x8 bb[2][8];
#pragma unroll
  for (int tt = 0; tt < 8; ++tt) {
    int nt = (tt < 4) ? (w * 4 + tt) : (16 + w * 4 + (tt - 4));
    bb[0][tt] = ldfrag(p1 + ((nt * 16 + 0) * 64 + l) * 8);
  }
  __syncthreads();   // quarter 0 staged

  // ---- GEMM1: gb = cond @ W_film (K=512, 4 quarters x 4 kt), overlapped.
  f32x4 acc1[4][8];
#pragma unroll
  for (int m = 0; m < 4; ++m)
#pragma unroll
    for (int n = 0; n < 8; ++n) acc1[m][n] = (f32x4){0.f, 0.f, 0.f, 0.f};

#pragma unroll
  for (int q = 0; q < 4; ++q) {
    // issue next-quarter cond loads + this-quarter x chunk loads (consumed at
    // the write window after this quarter's MFMAs -> latency fully hidden)
    float4 cn[8];
    if (q < 3) {
#pragma unroll
      for (int p = 0; p < 4; ++p)
#pragma unroll
        for (int j = 0; j < 2; ++j) {
          int g = p * 512 + t * 2 + j;
          cn[p * 2 + j] = *reinterpret_cast<const float4*>(
              cond + (size_t)(r0 + (g >> 5)) * 512 + (q + 1) * 128 + (g & 31) * 4);
        }
    }
    float4 xc[4];   // x chunk q: rows [q*16, q*16+16), pair p2 in 0..1
#pragma unroll
    for (int p2 = 0; p2 < 2; ++p2)
#pragma unroll
      for (int j = 0; j < 2; ++j) {
        int g = p2 * 512 + t * 2 + j;
        xc[p2 * 2 + j] = *reinterpret_cast<const float4*>(
            x + (size_t)(r0 + q * 16 + (g >> 6)) * 256 + (g & 63) * 4);
      }

#pragma unroll
    for (int kt = 0; kt < 4; ++kt) {
      int ktg = q * 4 + kt;
      const int cur = ktg & 1;
      if (ktg < 15) {
#pragma unroll
        for (int tt = 0; tt < 8; ++tt) {
          int nt = (tt < 4) ? (w * 4 + tt) : (16 + w * 4 + (tt - 4));
          bb[cur ^ 1][tt] = ldfrag(p1 + ((nt * 16 + (ktg + 1)) * 64 + l) * 8);
        }
      }
      bf16x8 afr[4];
#pragma unroll
      for (int m = 0; m < 4; ++m) {
        int row = m * 16 + l15;
        int byte = row * 256 + kt * 64 + lhi * 16;
        byte ^= ((row & 15) << 4);
        afr[m] = *reinterpret_cast<const bf16x8*>(condq + byte);
      }
      __builtin_amdgcn_s_setprio(1);
#pragma unroll
      for (int tt = 0; tt < 8; ++tt)
#pragma unroll
        for (int m = 0; m < 4; ++m)
          acc1[m][tt] = __builtin_amdgcn_mfma_f32_16x16x32_bf16(afr[m], bb[cur][tt], acc1[m][tt], 0, 0, 0);
      __builtin_amdgcn_s_setprio(0);
    }
    __syncthreads();   // all waves done reading quarter q
    if (q < 3) {
#pragma unroll
      for (int p = 0; p < 4; ++p) {
        int g = p * 512 + t * 2;
        int row = g >> 5, colf = (g & 31) * 4;
        int byte = row * 256 + colf * 2;
        byte ^= ((row & 15) << 4);
        *reinterpret_cast<bf16x8*>(condq + byte) = pack8(cn[p * 2], cn[p * 2 + 1]);
      }
    }
#pragma unroll
    for (int p2 = 0; p2 < 2; ++p2) {
      int g = p2 * 512 + t * 2;
      int row = q * 16 + (g >> 6);
      int byte = row * 512 + (g & 63) * 8;
      byte ^= ((row & 15) << 4);
      *reinterpret_cast<bf16x8*>(B + byte) = pack8(xc[p2 * 2], xc[p2 * 2 + 1]);
    }
    __syncthreads();   // next quarter (and x chunk) staged
  }
  // here: B holds all of x (bf16), condq dead.

  // ---- GEMM2 B preload, then FiLM: r1 = relu(gamma*x+beta) in place over x.
  bf16x8 bb2[2][4];
#pragma unroll
  for (int tt = 0; tt < 4; ++tt) {
    int nt = w * 4 + tt;
    bb2[0][tt] = ldfrag(pW1 + ((nt * 8 + 0) * 64 + l) * 8);
  }
  float xr[4][16];   // residual carried in registers
#pragma unroll
  for (int m = 0; m < 4; ++m) {
#pragma unroll
    for (int tt = 0; tt < 4; ++tt) {
      int colg = w * 64 + tt * 16 + l15;
#pragma unroll
      for (int reg = 0; reg < 4; ++reg) {
        int row = m * 16 + lhi * 4 + reg;
        int byte = row * 512 + colg * 2;
        byte ^= ((row & 15) << 4);
        float xv = bf2f(*reinterpret_cast<const ushort_t*>(B + byte));
        xr[m][tt * 4 + reg] = xv;
        float hv = fmaxf((acc1[m][tt][reg] + bgv[tt]) * xv + (acc1[m][4 + tt][reg] + bbv[tt]), 0.f);
        *reinterpret_cast<ushort_t*>(B + byte) = f2bf(hv);
      }
    }
  }
  __syncthreads();   // r1 ready

  // ---- GEMM2: acc2 = r1 @ W1 (K=256, 8 kt)
  f32x4 acc2[4][4];
#pragma unroll
  for (int m = 0; m < 4; ++m)
#pragma unroll
    for (int n = 0; n < 4; ++n) acc2[m][n] = (f32x4){0.f, 0.f, 0.f, 0.f};

#pragma unroll
  for (int kt = 0; kt < 8; ++kt) {
    const int cur = kt & 1;
    if (kt < 7) {
#pragma unroll
      for (int tt = 0; tt < 4; ++tt) {
        int nt = w * 4 + tt;
        bb2[cur ^ 1][tt] = ldfrag(pW1 + ((nt * 8 + (kt + 1)) * 64 + l) * 8);
      }
    }
    bf16x8 afr[4];
#pragma unroll
    for (int m = 0; m < 4; ++m) {
      int row = m * 16 + l15;
      int byte = row * 512 + kt * 64 + lhi * 16;
      byte ^= ((row & 15) << 4);
      afr[m] = *reinterpret_cast<const bf16x8*>(B + byte);
    }
    __builtin_amdgcn_s_setprio(1);
#pragma unroll
    for (int tt = 0; tt < 4; ++tt)
#pragma unroll
      for (int m = 0; m < 4; ++m)
        acc2[m][tt] = __builtin_amdgcn_mfma_f32_16x16x32_bf16(afr[m], bb2[cur][tt], acc2[m][tt], 0, 0, 0);
    __builtin_amdgcn_s_setprio(0);
  }
  // GEMM3 B preload before the barrier
  bf16x8 bb3[2][4];
#pragma unroll
  for (int tt = 0; tt < 4; ++tt) {
    int nt = w * 4 + tt;
    bb3[0][tt] = ldfrag(pW2 + ((nt * 8 + 0) * 64 + l) * 8);
  }
  __syncthreads();   // all r1 reads done -> in-place r2 safe

  // ---- r2 = relu(acc2 + b1) in place
#pragma unroll
  for (int tt = 0; tt < 4; ++tt) {
    int colg = w * 64 + tt * 16 + l15;
#pragma unroll
    for (int m = 0; m < 4; ++m) {
#pragma unroll
      for (int reg = 0; reg < 4; ++reg) {
        int row = m * 16 + lhi * 4 + reg;
        int byte = row * 512 + colg * 2;
        byte ^= ((row & 15) << 4);
        *reinterpret_cast<ushort_t*>(B + byte) = f2bf(fmaxf(acc2[m][tt][reg] + b1v[tt], 0.f));
      }
    }
  }
  __syncthreads();   // r2 ready

  // ---- GEMM3: acc3 = r2 @ W2 (K=256, 8 kt)
  f32x4 acc3[4][4];
#pragma unroll
  for (int m = 0; m < 4; ++m)
#pragma unroll
    for (int n = 0; n < 4; ++n) acc3[m][n] = (f32x4){0.f, 0.f, 0.f, 0.f};

#pragma unroll
  for (int kt = 0; kt < 8; ++kt) {
    const int cur = kt & 1;
    if (kt < 7) {
#pragma unroll
      for (int tt = 0; tt < 4; ++tt) {
        int nt = w * 4 + tt;
        bb3[cur ^ 1][tt] = ldfrag(pW2 + ((nt * 8 + (kt + 1)) * 64 + l) * 8);
      }
    }
    bf16x8 afr[4];
#pragma unroll
    for (int m = 0; m < 4; ++m) {
      int row = m * 16 + l15;
      int byte = row * 512 + kt * 64 + lhi * 16;
      byte ^= ((row & 15) << 4);
      afr[m] = *reinterpret_cast<const bf16x8*>(B + byte);
    }
    __builtin_amdgcn_s_setprio(1);
#pragma unroll
    for (int tt = 0; tt < 4; ++tt)
#pragma unroll
      for (int m = 0; m < 4; ++m)
        acc3[m][tt] = __builtin_amdgcn_mfma_f32_16x16x32_bf16(afr[m], bb3[cur][tt], acc3[m][tt], 0, 0, 0);
    __builtin_amdgcn_s_setprio(0);
  }
  __syncthreads();   // all r2 reads done -> B free for epilogue

  // ---- epilogue: residual+bias added in acc layout (registers), fp32 tile
  // through B ([32][256] per half), coalesced nontemporal float4 stores.
#pragma unroll
  for (int hh = 0; hh < 2; ++hh) {
    if (hh) __syncthreads();   // half-0 stores done before overwrite
#pragma unroll
    for (int tt = 0; tt < 4; ++tt) {
#pragma unroll
      for (int mm = 0; mm < 2; ++mm) {
        int m = hh * 2 + mm;
#pragma unroll
        for (int reg = 0; reg < 4; ++reg) {
          int r = mm * 16 + lhi * 4 + reg;
          int colg = w * 64 + tt * 16 + l15;
          int byte = r * 1024 + colg * 4;
          byte ^= ((r & 15) << 4);
          *reinterpret_cast<float*>(B + byte) =
              acc3[m][tt][reg] + b2v[tt] + xr[m][tt * 4 + reg];
        }
      }
    }
    __syncthreads();
#pragma unroll
    for (int i = 0; i < 8; ++i) {
      int row = i * 4 + w;           // wave-uniform row
      int byte = row * 1024 + l * 16;
      byte ^= ((row & 15) << 4);
      f32x4 v = *reinterpret_cast<const f32x4*>(B + byte);
      f32x4* op = reinterpret_cast<f32x4*>(out + (size_t)(r0 + hh * 32 + row) * 256 + l * 4);
      __builtin_nontemporal_store(v, op);
    }
  }
}

extern "C" void kernel_launch(void* const* d_in, const int* in_sizes, int n_in,
                              void* d_out, int out_size, void* d_ws, size_t ws_size,
                              hipStream_t stream) {
  const float* x      = (const float*)d_in[0];
  const float* cond   = (const float*)d_in[1];
  const float* W_film = (const float*)d_in[2];
  const float* b_film = (const float*)d_in[3];
  const float* W1     = (const float*)d_in[4];
  const float* b1     = (const float*)d_in[5];
  const float* W2     = (const float*)d_in[6];
  const float* b2     = (const float*)d_in[7];
  float* out = (float*)d_out;

  ushort_t* p1  = (ushort_t*)d_ws;      // 512KB
  ushort_t* pW1 = p1 + 262144;          // 128KB
  ushort_t* pW2 = pW1 + 65536;          // 128KB

  hipLaunchKernelGGL(pack_weights, dim3(192), dim3(256), 0, stream,
                     W_film, W1, W2, p1, pW1, pW2);
  hipLaunchKernelGGL(film_fused, dim3(65536 / 64), dim3(256), 0, stream,
                     x, cond, b_film, b1, b2, p1, pW1, pW2, out);
}

// Round 8
// 174.127 us; speedup vs baseline: 4.3614x; 4.3614x over previous
//
#include <hip/hip_runtime.h>
#include <hip/hip_bf16.h>

// FiLM + 2-layer preact resnet, fully fused. N=65536, H=256, C=512.
// Round 7 (resubmit after infra failure): gamma/beta TIME-SPLIT GEMM1
// (acc[4][4] per pass, no spill) over full-K cond in 64KB LDS (no mid-loop
// restage). x staged to LDS after cond dies and kept for the epilogue
// residual. Flat 32-step GEMM1 loop with 2-deep B-panel register pipeline
// crossing the pass boundary.

typedef __attribute__((ext_vector_type(8))) short bf16x8;   // 8 bf16 = 4 VGPR
typedef __attribute__((ext_vector_type(4))) float f32x4;    // MFMA C/D

typedef unsigned short ushort_t;
typedef unsigned int uint_t;

__device__ __forceinline__ ushort_t f2bf(float f) {
  union { float f; uint_t u; } v; v.f = f;
  uint_t u = v.u;
  return (ushort_t)((u + 0x7FFFu + ((u >> 16) & 1u)) >> 16);  // RNE
}
__device__ __forceinline__ float bf2f(ushort_t s) {
  union { uint_t u; float f; } v; v.u = ((uint_t)s) << 16;
  return v.f;
}
__device__ __forceinline__ bf16x8 ldfrag(const ushort_t* p) {
  return *reinterpret_cast<const bf16x8*>(p);
}
__device__ __forceinline__ bf16x8 pack8(float4 a, float4 b) {
  union { bf16x8 v; ushort_t s[8]; } h;
  h.s[0]=f2bf(a.x); h.s[1]=f2bf(a.y); h.s[2]=f2bf(a.z); h.s[3]=f2bf(a.w);
  h.s[4]=f2bf(b.x); h.s[5]=f2bf(b.y); h.s[6]=f2bf(b.z); h.s[7]=f2bf(b.w);
  return h.v;
}

// ---------------------------------------------------------------------------
// Pack weights (fp32 row-major [K][Ncols]) into bf16 MFMA-B fragment order:
//   p[((nt*KT + kt)*64 + lane)*8 + j] = W[kt*32 + (lane>>4)*8 + j][nt*16 + (lane&15)]
// ---------------------------------------------------------------------------
__global__ void pack_weights(const float* __restrict__ Wf,
                             const float* __restrict__ W1,
                             const float* __restrict__ W2,
                             ushort_t* __restrict__ p1,
                             ushort_t* __restrict__ pW1,
                             ushort_t* __restrict__ pW2) {
  int u = blockIdx.x * 256 + threadIdx.x;
  if (u < 32768) {
    int lane = u & 63, rest = u >> 6;
    int kt = rest & 15;
    int kb = kt * 32 + (lane >> 4) * 8;
    int col = (rest >> 4) * 16 + (lane & 15);
#pragma unroll
    for (int j = 0; j < 8; ++j)
      p1[(size_t)u * 8 + j] = f2bf(Wf[(size_t)(kb + j) * 512 + col]);
  } else if (u < 40960) {
    int v = u - 32768;
    int lane = v & 63;
    int kt = (v >> 6) & 7;
    int kb = kt * 32 + (lane >> 4) * 8;
    int col = (v >> 9) * 16 + (lane & 15);
#pragma unroll
    for (int j = 0; j < 8; ++j)
      pW1[(size_t)v * 8 + j] = f2bf(W1[(size_t)(kb + j) * 256 + col]);
  } else if (u < 49152) {
    int v = u - 40960;
    int lane = v & 63;
    int kt = (v >> 6) & 7;
    int kb = kt * 32 + (lane >> 4) * 8;
    int col = (v >> 9) * 16 + (lane & 15);
#pragma unroll
    for (int j = 0; j < 8; ++j)
      pW2[(size_t)v * 8 + j] = f2bf(W2[(size_t)(kb + j) * 256 + col]);
  }
}

// ---------------------------------------------------------------------------
// 1 workgroup = 64 rows, 4 waves; wave w owns output cols [w*64, w*64+64).
// LDS 64KB, region A=[0,32K) B=[32K,64K):
//   phase 1: cond bf16 [64][512] across A+B (byte = row*1024 + k*2, swz)
//   phase 2: A = x bf16 [64][256] (persists to epilogue residual)
//            B = r1 bf16 [64][256] -> r2 -> epilogue fp32 [32][256] halves
// XOR swizzle: byte ^= (row&15)<<4.
// ---------------------------------------------------------------------------
__global__ __launch_bounds__(256, 2)
void film_fused(const float* __restrict__ x, const float* __restrict__ cond,
                const float* __restrict__ b_film, const float* __restrict__ b1,
                const float* __restrict__ b2,
                const ushort_t* __restrict__ p1, const ushort_t* __restrict__ pW1,
                const ushort_t* __restrict__ pW2, float* __restrict__ out) {
  __shared__ __align__(16) char lds[65536];
  char* A = lds;
  char* B = lds + 32768;
  const int r0 = blockIdx.x * 64;
  const int t = threadIdx.x;
  const int w = t >> 6;
  const int l = t & 63;
  const int l15 = l & 15;
  const int lhi = l >> 4;

  // ---- per-lane bias preloads (tiny, L2-hot)
  float bgv[4], bbv[4], b1v[4], b2v[4];
#pragma unroll
  for (int tt = 0; tt < 4; ++tt) {
    int colg = w * 64 + tt * 16 + l15;
    bgv[tt] = b_film[colg];
    bbv[tt] = b_film[256 + colg];
    b1v[tt] = b1[colg];
    b2v[tt] = b2[colg];
  }

  // ---- stage cond full-K -> bf16 LDS [64][512] swz (A+B)
#pragma unroll
  for (int it = 0; it < 16; ++it) {
    int u = it * 256 + t;
    int row = u >> 6, k8 = u & 63;   // [64 rows][64 units of 8 cols]
    const float4* cs = reinterpret_cast<const float4*>(cond + (size_t)(r0 + row) * 512 + k8 * 8);
    float4 a = cs[0], b = cs[1];
    int byte = row * 1024 + k8 * 16;
    byte ^= ((row & 15) << 4);
    *reinterpret_cast<bf16x8*>(lds + byte) = pack8(a, b);
  }

  // ---- GEMM1 B preload (s=0: gamma, kt=0) before the barrier
  bf16x8 bb[2][4];
#pragma unroll
  for (int tt = 0; tt < 4; ++tt) {
    int nt = w * 4 + tt;   // gamma panels
    bb[0][tt] = ldfrag(p1 + ((size_t)(nt * 16 + 0) * 64 + l) * 8);
  }
  __syncthreads();   // B1: cond staged

  // ---- GEMM1: flat 32 steps. s<16: gamma pass (acc_g), s>=16: beta pass
  // (acc_b, panels nt+16). B-panels 2-deep register pipeline across passes.
  f32x4 acc_g[4][4], acc_b[4][4];
#pragma unroll
  for (int m = 0; m < 4; ++m)
#pragma unroll
    for (int n = 0; n < 4; ++n) {
      acc_g[m][n] = (f32x4){0.f, 0.f, 0.f, 0.f};
      acc_b[m][n] = (f32x4){0.f, 0.f, 0.f, 0.f};
    }

#pragma unroll
  for (int s = 0; s < 32; ++s) {
    const int cur = s & 1;
    if (s < 31) {
      const int sn = s + 1;
      const int ktn = sn & 15;
      const int base = (sn >> 4) ? 16 : 0;
#pragma unroll
      for (int tt = 0; tt < 4; ++tt) {
        int nt = base + w * 4 + tt;
        bb[cur ^ 1][tt] = ldfrag(p1 + ((size_t)(nt * 16 + ktn) * 64 + l) * 8);
      }
    }
    const int kt = s & 15;
    bf16x8 afr[4];
#pragma unroll
    for (int m = 0; m < 4; ++m) {
      int row = m * 16 + l15;
      int byte = row * 1024 + kt * 64 + lhi * 16;
      byte ^= ((row & 15) << 4);
      afr[m] = *reinterpret_cast<const bf16x8*>(lds + byte);
    }
    __builtin_amdgcn_s_setprio(1);
    if (s < 16) {
#pragma unroll
      for (int tt = 0; tt < 4; ++tt)
#pragma unroll
        for (int m = 0; m < 4; ++m)
          acc_g[m][tt] = __builtin_amdgcn_mfma_f32_16x16x32_bf16(afr[m], bb[cur][tt], acc_g[m][tt], 0, 0, 0);
    } else {
#pragma unroll
      for (int tt = 0; tt < 4; ++tt)
#pragma unroll
        for (int m = 0; m < 4; ++m)
          acc_b[m][tt] = __builtin_amdgcn_mfma_f32_16x16x32_bf16(afr[m], bb[cur][tt], acc_b[m][tt], 0, 0, 0);
    }
    __builtin_amdgcn_s_setprio(0);
  }

  // ---- issue x loads (16 float4/thread) + GEMM2 B preload, then barrier:
  // load latency hides under the barrier drain.
  float4 xl[16];
#pragma unroll
  for (int it = 0; it < 8; ++it) {
    int g = it * 256 + t;            // [64 rows][32 units of 8 floats]
    int row = g >> 5, c8 = g & 31;
    const float4* xs = reinterpret_cast<const float4*>(x + (size_t)(r0 + row) * 256 + c8 * 8);
    xl[it * 2] = xs[0];
    xl[it * 2 + 1] = xs[1];
  }
  bf16x8 bb2[2][4];
#pragma unroll
  for (int tt = 0; tt < 4; ++tt) {
    int nt = w * 4 + tt;
    bb2[0][tt] = ldfrag(pW1 + ((size_t)(nt * 8 + 0) * 64 + l) * 8);
  }
  __syncthreads();   // B2: all cond reads done -> LDS reusable

  // ---- write x bf16 -> A [64][256] swz
#pragma unroll
  for (int it = 0; it < 8; ++it) {
    int g = it * 256 + t;
    int row = g >> 5, c8 = g & 31;
    int byte = row * 512 + c8 * 16;
    byte ^= ((row & 15) << 4);
    *reinterpret_cast<bf16x8*>(A + byte) = pack8(xl[it * 2], xl[it * 2 + 1]);
  }
  __syncthreads();   // B3: x staged

  // ---- FiLM: r1 = relu((acc_g+bg)*x + (acc_b+bb)) -> bf16 into B
#pragma unroll
  for (int m = 0; m < 4; ++m) {
#pragma unroll
    for (int tt = 0; tt < 4; ++tt) {
      int colg = w * 64 + tt * 16 + l15;
#pragma unroll
      for (int reg = 0; reg < 4; ++reg) {
        int row = m * 16 + lhi * 4 + reg;
        int byte = row * 512 + colg * 2;
        byte ^= ((row & 15) << 4);
        float xv = bf2f(*reinterpret_cast<const ushort_t*>(A + byte));
        float hv = fmaxf((acc_g[m][tt][reg] + bgv[tt]) * xv + (acc_b[m][tt][reg] + bbv[tt]), 0.f);
        *reinterpret_cast<ushort_t*>(B + byte) = f2bf(hv);
      }
    }
  }
  __syncthreads();   // B4: r1 ready

  // ---- GEMM2: acc2 = r1 @ W1 (K=256, 8 kt), B 2-deep pipelined
  f32x4 acc2[4][4];
#pragma unroll
  for (int m = 0; m < 4; ++m)
#pragma unroll
    for (int n = 0; n < 4; ++n) acc2[m][n] = (f32x4){0.f, 0.f, 0.f, 0.f};

#pragma unroll
  for (int kt = 0; kt < 8; ++kt) {
    const int cur = kt & 1;
    if (kt < 7) {
#pragma unroll
      for (int tt = 0; tt < 4; ++tt) {
        int nt = w * 4 + tt;
        bb2[cur ^ 1][tt] = ldfrag(pW1 + ((size_t)(nt * 8 + (kt + 1)) * 64 + l) * 8);
      }
    }
    bf16x8 afr[4];
#pragma unroll
    for (int m = 0; m < 4; ++m) {
      int row = m * 16 + l15;
      int byte = row * 512 + kt * 64 + lhi * 16;
      byte ^= ((row & 15) << 4);
      afr[m] = *reinterpret_cast<const bf16x8*>(B + byte);
    }
    __builtin_amdgcn_s_setprio(1);
#pragma unroll
    for (int tt = 0; tt < 4; ++tt)
#pragma unroll
      for (int m = 0; m < 4; ++m)
        acc2[m][tt] = __builtin_amdgcn_mfma_f32_16x16x32_bf16(afr[m], bb2[cur][tt], acc2[m][tt], 0, 0, 0);
    __builtin_amdgcn_s_setprio(0);
  }
  // GEMM3 B preload before the barrier
  bf16x8 bb3[2][4];
#pragma unroll
  for (int tt = 0; tt < 4; ++tt) {
    int nt = w * 4 + tt;
    bb3[0][tt] = ldfrag(pW2 + ((size_t)(nt * 8 + 0) * 64 + l) * 8);
  }
  __syncthreads();   // B5: all r1 reads done -> r2 may overwrite B

  // ---- r2 = relu(acc2 + b1) -> B
#pragma unroll
  for (int tt = 0; tt < 4; ++tt) {
    int colg = w * 64 + tt * 16 + l15;
#pragma unroll
    for (int m = 0; m < 4; ++m) {
#pragma unroll
      for (int reg = 0; reg < 4; ++reg) {
        int row = m * 16 + lhi * 4 + reg;
        int byte = row * 512 + colg * 2;
        byte ^= ((row & 15) << 4);
        *reinterpret_cast<ushort_t*>(B + byte) = f2bf(fmaxf(acc2[m][tt][reg] + b1v[tt], 0.f));
      }
    }
  }
  __syncthreads();   // B6: r2 ready

  // ---- GEMM3: acc3 = r2 @ W2 (K=256, 8 kt)
  f32x4 acc3[4][4];
#pragma unroll
  for (int m = 0; m < 4; ++m)
#pragma unroll
    for (int n = 0; n < 4; ++n) acc3[m][n] = (f32x4){0.f, 0.f, 0.f, 0.f};

#pragma unroll
  for (int kt = 0; kt < 8; ++kt) {
    const int cur = kt & 1;
    if (kt < 7) {
#pragma unroll
      for (int tt = 0; tt < 4; ++tt) {
        int nt = w * 4 + tt;
        bb3[cur ^ 1][tt] = ldfrag(pW2 + ((size_t)(nt * 8 + (kt + 1)) * 64 + l) * 8);
      }
    }
    bf16x8 afr[4];
#pragma unroll
    for (int m = 0; m < 4; ++m) {
      int row = m * 16 + l15;
      int byte = row * 512 + kt * 64 + lhi * 16;
      byte ^= ((row & 15) << 4);
      afr[m] = *reinterpret_cast<const bf16x8*>(B + byte);
    }
    __builtin_amdgcn_s_setprio(1);
#pragma unroll
    for (int tt = 0; tt < 4; ++tt)
#pragma unroll
      for (int m = 0; m < 4; ++m)
        acc3[m][tt] = __builtin_amdgcn_mfma_f32_16x16x32_bf16(afr[m], bb3[cur][tt], acc3[m][tt], 0, 0, 0);
    __builtin_amdgcn_s_setprio(0);
  }
  __syncthreads();   // B7: all r2 reads done -> B free for epilogue

  // ---- epilogue: two 32-row halves through B (fp32 [32][256] swz),
  // residual read coalesced from A (x bf16), nontemporal float4 stores.
#pragma unroll
  for (int hh = 0; hh < 2; ++hh) {
    if (hh) __syncthreads();   // half-0 reads done before overwrite
#pragma unroll
    for (int tt = 0; tt < 4; ++tt) {
      int colg = w * 64 + tt * 16 + l15;
#pragma unroll
      for (int mm = 0; mm < 2; ++mm) {
        int m = hh * 2 + mm;
#pragma unroll
        for (int reg = 0; reg < 4; ++reg) {
          int r = mm * 16 + lhi * 4 + reg;
          int byte = r * 1024 + colg * 4;
          byte ^= ((r & 15) << 4);
          *reinterpret_cast<float*>(B + byte) = acc3[m][tt][reg] + b2v[tt];
        }
      }
    }
    __syncthreads();
#pragma unroll
    for (int i = 0; i < 8; ++i) {
      int r = i * 4 + w;               // wave-uniform row within half
      int byte = r * 1024 + l * 16;
      byte ^= ((r & 15) << 4);
      f32x4 v = *reinterpret_cast<const f32x4*>(B + byte);
      int grow = hh * 32 + r;
      int xbyte = grow * 512 + l * 8;  // 4 bf16 of x
      xbyte ^= ((grow & 15) << 4);
      const ushort_t* xp = reinterpret_cast<const ushort_t*>(A + xbyte);
      v.x += bf2f(xp[0]); v.y += bf2f(xp[1]); v.z += bf2f(xp[2]); v.w += bf2f(xp[3]);
      f32x4* op = reinterpret_cast<f32x4*>(out + (size_t)(r0 + grow) * 256 + l * 4);
      __builtin_nontemporal_store(v, op);
    }
  }
}

extern "C" void kernel_launch(void* const* d_in, const int* in_sizes, int n_in,
                              void* d_out, int out_size, void* d_ws, size_t ws_size,
                              hipStream_t stream) {
  const float* x      = (const float*)d_in[0];
  const float* cond   = (const float*)d_in[1];
  const float* W_film = (const float*)d_in[2];
  const float* b_film = (const float*)d_in[3];
  const float* W1     = (const float*)d_in[4];
  const float* b1     = (const float*)d_in[5];
  const float* W2     = (const float*)d_in[6];
  const float* b2     = (const float*)d_in[7];
  float* out = (float*)d_out;

  ushort_t* p1  = (ushort_t*)d_ws;      // 512KB
  ushort_t* pW1 = p1 + 262144;          // 128KB
  ushort_t* pW2 = pW1 + 65536;          // 128KB

  hipLaunchKernelGGL(pack_weights, dim3(192), dim3(256), 0, stream,
                     W_film, W1, W2, p1, pW1, pW2);
  hipLaunchKernelGGL(film_fused, dim3(65536 / 64), dim3(256), 0, stream,
                     x, cond, b_film, b1, b2, p1, pW1, pW2, out);
}

// Round 10
// 103.355 us; speedup vs baseline: 7.3479x; 1.6847x over previous
//
#include <hip/hip_runtime.h>
#include <hip/hip_bf16.h>

// FiLM + 2-layer preact resnet, fully fused. N=65536, H=256, C=512.
// Round 9 (resubmit after infra failure): same structure as round 7 (full-K
// cond in LDS, gamma/beta time-split GEMM1, x in LDS for FiLM+residual) BUT
// __launch_bounds__(256,1): empirical law VGPR budget = 256/arg2 (r1/4/8:
// arg2=2 -> 128 box -> spill). Budget 256 -> no spill. GEMM1 B-pipeline
// 3 slots; x staging split into two 32-row chunks.

typedef __attribute__((ext_vector_type(8))) short bf16x8;   // 8 bf16 = 4 VGPR
typedef __attribute__((ext_vector_type(4))) float f32x4;    // MFMA C/D

typedef unsigned short ushort_t;
typedef unsigned int uint_t;

__device__ __forceinline__ ushort_t f2bf(float f) {
  union { float f; uint_t u; } v; v.f = f;
  uint_t u = v.u;
  return (ushort_t)((u + 0x7FFFu + ((u >> 16) & 1u)) >> 16);  // RNE
}
__device__ __forceinline__ float bf2f(ushort_t s) {
  union { uint_t u; float f; } v; v.u = ((uint_t)s) << 16;
  return v.f;
}
__device__ __forceinline__ bf16x8 ldfrag(const ushort_t* p) {
  return *reinterpret_cast<const bf16x8*>(p);
}
__device__ __forceinline__ bf16x8 pack8(float4 a, float4 b) {
  union { bf16x8 v; ushort_t s[8]; } h;
  h.s[0]=f2bf(a.x); h.s[1]=f2bf(a.y); h.s[2]=f2bf(a.z); h.s[3]=f2bf(a.w);
  h.s[4]=f2bf(b.x); h.s[5]=f2bf(b.y); h.s[6]=f2bf(b.z); h.s[7]=f2bf(b.w);
  return h.v;
}

// ---------------------------------------------------------------------------
// Pack weights (fp32 row-major [K][Ncols]) into bf16 MFMA-B fragment order:
//   p[((nt*KT + kt)*64 + lane)*8 + j] = W[kt*32 + (lane>>4)*8 + j][nt*16 + (lane&15)]
// ---------------------------------------------------------------------------
__global__ void pack_weights(const float* __restrict__ Wf,
                             const float* __restrict__ W1,
                             const float* __restrict__ W2,
                             ushort_t* __restrict__ p1,
                             ushort_t* __restrict__ pW1,
                             ushort_t* __restrict__ pW2) {
  int u = blockIdx.x * 256 + threadIdx.x;
  if (u < 32768) {
    int lane = u & 63, rest = u >> 6;
    int kt = rest & 15;
    int kb = kt * 32 + (lane >> 4) * 8;
    int col = (rest >> 4) * 16 + (lane & 15);
#pragma unroll
    for (int j = 0; j < 8; ++j)
      p1[(size_t)u * 8 + j] = f2bf(Wf[(size_t)(kb + j) * 512 + col]);
  } else if (u < 40960) {
    int v = u - 32768;
    int lane = v & 63;
    int kt = (v >> 6) & 7;
    int kb = kt * 32 + (lane >> 4) * 8;
    int col = (v >> 9) * 16 + (lane & 15);
#pragma unroll
    for (int j = 0; j < 8; ++j)
      pW1[(size_t)v * 8 + j] = f2bf(W1[(size_t)(kb + j) * 256 + col]);
  } else if (u < 49152) {
    int v = u - 40960;
    int lane = v & 63;
    int kt = (v >> 6) & 7;
    int kb = kt * 32 + (lane >> 4) * 8;
    int col = (v >> 9) * 16 + (lane & 15);
#pragma unroll
    for (int j = 0; j < 8; ++j)
      pW2[(size_t)v * 8 + j] = f2bf(W2[(size_t)(kb + j) * 256 + col]);
  }
}

// ---------------------------------------------------------------------------
// 1 workgroup = 64 rows, 4 waves; wave w owns output cols [w*64, w*64+64).
// LDS 64KB, region A=[0,32K) B=[32K,64K):
//   phase 1: cond bf16 [64][512] across A+B (byte = row*1024 + k*2, swz)
//   phase 2: A = x bf16 [64][256] (persists to epilogue residual)
//            B = r1 bf16 [64][256] -> r2 -> epilogue fp32 [32][256] halves
// XOR swizzle: byte ^= (row&15)<<4.
// LDS (64KB) caps occupancy at 2 blocks/CU; launch_bounds(256,1) gives the
// allocator the full 256-VGPR budget (arg2=2 empirically boxes it at 128).
// ---------------------------------------------------------------------------
__global__ __launch_bounds__(256, 1)
void film_fused(const float* __restrict__ x, const float* __restrict__ cond,
                const float* __restrict__ b_film, const float* __restrict__ b1,
                const float* __restrict__ b2,
                const ushort_t* __restrict__ p1, const ushort_t* __restrict__ pW1,
                const ushort_t* __restrict__ pW2, float* __restrict__ out) {
  __shared__ __align__(16) char lds[65536];
  char* A = lds;
  char* B = lds + 32768;
  const int r0 = blockIdx.x * 64;
  const int t = threadIdx.x;
  const int w = t >> 6;
  const int l = t & 63;
  const int l15 = l & 15;
  const int lhi = l >> 4;

  // ---- per-lane bias preloads (tiny, L2-hot)
  float bgv[4], bbv[4], b1v[4], b2v[4];
#pragma unroll
  for (int tt = 0; tt < 4; ++tt) {
    int colg = w * 64 + tt * 16 + l15;
    bgv[tt] = b_film[colg];
    bbv[tt] = b_film[256 + colg];
    b1v[tt] = b1[colg];
    b2v[tt] = b2[colg];
  }

  // ---- stage cond full-K -> bf16 LDS [64][512] swz (A+B)
#pragma unroll
  for (int it = 0; it < 16; ++it) {
    int u = it * 256 + t;
    int row = u >> 6, k8 = u & 63;   // [64 rows][64 units of 8 cols]
    const float4* cs = reinterpret_cast<const float4*>(cond + (size_t)(r0 + row) * 512 + k8 * 8);
    float4 a = cs[0], b = cs[1];
    int byte = row * 1024 + k8 * 16;
    byte ^= ((row & 15) << 4);
    *reinterpret_cast<bf16x8*>(lds + byte) = pack8(a, b);
  }

  // ---- GEMM1 B preload (s=0,1 -> slots 0,1) before the barrier
  bf16x8 bb[3][4];
#pragma unroll
  for (int tt = 0; tt < 4; ++tt) {
    int nt = w * 4 + tt;   // gamma panels (s=0 and s=1 are both gamma)
    bb[0][tt] = ldfrag(p1 + ((size_t)(nt * 16 + 0) * 64 + l) * 8);
    bb[1][tt] = ldfrag(p1 + ((size_t)(nt * 16 + 1) * 64 + l) * 8);
  }
  __syncthreads();   // B1: cond staged

  // ---- GEMM1: flat 32 steps. s<16: gamma pass (acc_g), s>=16: beta pass
  // (acc_b, panels nt+16). B-panels 3-deep register pipeline across passes.
  f32x4 acc_g[4][4], acc_b[4][4];
#pragma unroll
  for (int m = 0; m < 4; ++m)
#pragma unroll
    for (int n = 0; n < 4; ++n) {
      acc_g[m][n] = (f32x4){0.f, 0.f, 0.f, 0.f};
      acc_b[m][n] = (f32x4){0.f, 0.f, 0.f, 0.f};
    }

#pragma unroll
  for (int s = 0; s < 32; ++s) {
    const int cur = s % 3;
    if (s < 30) {
      const int sn = s + 2;
      const int ktn = sn & 15;
      const int base = (sn >> 4) ? 16 : 0;
      const int slot = sn % 3;
#pragma unroll
      for (int tt = 0; tt < 4; ++tt) {
        int nt = base + w * 4 + tt;
        bb[slot][tt] = ldfrag(p1 + ((size_t)(nt * 16 + ktn) * 64 + l) * 8);
      }
    }
    const int kt = s & 15;
    bf16x8 afr[4];
#pragma unroll
    for (int m = 0; m < 4; ++m) {
      int row = m * 16 + l15;
      int byte = row * 1024 + kt * 64 + lhi * 16;
      byte ^= ((row & 15) << 4);
      afr[m] = *reinterpret_cast<const bf16x8*>(lds + byte);
    }
    __builtin_amdgcn_s_setprio(1);
    if (s < 16) {
#pragma unroll
      for (int tt = 0; tt < 4; ++tt)
#pragma unroll
        for (int m = 0; m < 4; ++m)
          acc_g[m][tt] = __builtin_amdgcn_mfma_f32_16x16x32_bf16(afr[m], bb[cur][tt], acc_g[m][tt], 0, 0, 0);
    } else {
#pragma unroll
      for (int tt = 0; tt < 4; ++tt)
#pragma unroll
        for (int m = 0; m < 4; ++m)
          acc_b[m][tt] = __builtin_amdgcn_mfma_f32_16x16x32_bf16(afr[m], bb[cur][tt], acc_b[m][tt], 0, 0, 0);
    }
    __builtin_amdgcn_s_setprio(0);
  }

  // ---- x staging in two 32-row chunks (32 regs each) + GEMM2 B preload.
  // Chunk-0 loads issue before B2 so their latency hides under the drain.
  float4 xl[8];
#pragma unroll
  for (int it = 0; it < 4; ++it) {
    int g = it * 256 + t;            // rows 0..31: [32 rows][32 units of 8]
    int row = g >> 5, c8 = g & 31;
    const float4* xs = reinterpret_cast<const float4*>(x + (size_t)(r0 + row) * 256 + c8 * 8);
    xl[it * 2] = xs[0];
    xl[it * 2 + 1] = xs[1];
  }
  bf16x8 bb2[2][4];
#pragma unroll
  for (int tt = 0; tt < 4; ++tt) {
    int nt = w * 4 + tt;
    bb2[0][tt] = ldfrag(pW1 + ((size_t)(nt * 8 + 0) * 64 + l) * 8);
  }
  __syncthreads();   // B2: all cond reads done -> LDS reusable

  // write chunk 0 -> A rows 0..31; then load+write chunk 1
#pragma unroll
  for (int it = 0; it < 4; ++it) {
    int g = it * 256 + t;
    int row = g >> 5, c8 = g & 31;
    int byte = row * 512 + c8 * 16;
    byte ^= ((row & 15) << 4);
    *reinterpret_cast<bf16x8*>(A + byte) = pack8(xl[it * 2], xl[it * 2 + 1]);
  }
  float4 xl2[8];
#pragma unroll
  for (int it = 0; it < 4; ++it) {
    int g = it * 256 + t;            // rows 32..63
    int row = 32 + (g >> 5), c8 = g & 31;
    const float4* xs = reinterpret_cast<const float4*>(x + (size_t)(r0 + row) * 256 + c8 * 8);
    xl2[it * 2] = xs[0];
    xl2[it * 2 + 1] = xs[1];
  }
#pragma unroll
  for (int it = 0; it < 4; ++it) {
    int g = it * 256 + t;
    int row = 32 + (g >> 5), c8 = g & 31;
    int byte = row * 512 + c8 * 16;
    byte ^= ((row & 15) << 4);
    *reinterpret_cast<bf16x8*>(A + byte) = pack8(xl2[it * 2], xl2[it * 2 + 1]);
  }
  __syncthreads();   // B3: x staged

  // ---- FiLM: r1 = relu((acc_g+bg)*x + (acc_b+bb)) -> bf16 into B
#pragma unroll
  for (int m = 0; m < 4; ++m) {
#pragma unroll
    for (int tt = 0; tt < 4; ++tt) {
      int colg = w * 64 + tt * 16 + l15;
#pragma unroll
      for (int reg = 0; reg < 4; ++reg) {
        int row = m * 16 + lhi * 4 + reg;
        int byte = row * 512 + colg * 2;
        byte ^= ((row & 15) << 4);
        float xv = bf2f(*reinterpret_cast<const ushort_t*>(A + byte));
        float hv = fmaxf((acc_g[m][tt][reg] + bgv[tt]) * xv + (acc_b[m][tt][reg] + bbv[tt]), 0.f);
        *reinterpret_cast<ushort_t*>(B + byte) = f2bf(hv);
      }
    }
  }
  __syncthreads();   // B4: r1 ready

  // ---- GEMM2: acc2 = r1 @ W1 (K=256, 8 kt), B 2-deep pipelined
  f32x4 acc2[4][4];
#pragma unroll
  for (int m = 0; m < 4; ++m)
#pragma unroll
    for (int n = 0; n < 4; ++n) acc2[m][n] = (f32x4){0.f, 0.f, 0.f, 0.f};

#pragma unroll
  for (int kt = 0; kt < 8; ++kt) {
    const int cur = kt & 1;
    if (kt < 7) {
#pragma unroll
      for (int tt = 0; tt < 4; ++tt) {
        int nt = w * 4 + tt;
        bb2[cur ^ 1][tt] = ldfrag(pW1 + ((size_t)(nt * 8 + (kt + 1)) * 64 + l) * 8);
      }
    }
    bf16x8 afr[4];
#pragma unroll
    for (int m = 0; m < 4; ++m) {
      int row = m * 16 + l15;
      int byte = row * 512 + kt * 64 + lhi * 16;
      byte ^= ((row & 15) << 4);
      afr[m] = *reinterpret_cast<const bf16x8*>(B + byte);
    }
    __builtin_amdgcn_s_setprio(1);
#pragma unroll
    for (int tt = 0; tt < 4; ++tt)
#pragma unroll
      for (int m = 0; m < 4; ++m)
        acc2[m][tt] = __builtin_amdgcn_mfma_f32_16x16x32_bf16(afr[m], bb2[cur][tt], acc2[m][tt], 0, 0, 0);
    __builtin_amdgcn_s_setprio(0);
  }
  // GEMM3 B preload before the barrier
  bf16x8 bb3[2][4];
#pragma unroll
  for (int tt = 0; tt < 4; ++tt) {
    int nt = w * 4 + tt;
    bb3[0][tt] = ldfrag(pW2 + ((size_t)(nt * 8 + 0) * 64 + l) * 8);
  }
  __syncthreads();   // B5: all r1 reads done -> r2 may overwrite B

  // ---- r2 = relu(acc2 + b1) -> B
#pragma unroll
  for (int tt = 0; tt < 4; ++tt) {
    int colg = w * 64 + tt * 16 + l15;
#pragma unroll
    for (int m = 0; m < 4; ++m) {
#pragma unroll
      for (int reg = 0; reg < 4; ++reg) {
        int row = m * 16 + lhi * 4 + reg;
        int byte = row * 512 + colg * 2;
        byte ^= ((row & 15) << 4);
        *reinterpret_cast<ushort_t*>(B + byte) = f2bf(fmaxf(acc2[m][tt][reg] + b1v[tt], 0.f));
      }
    }
  }
  __syncthreads();   // B6: r2 ready

  // ---- GEMM3: acc3 = r2 @ W2 (K=256, 8 kt)
  f32x4 acc3[4][4];
#pragma unroll
  for (int m = 0; m < 4; ++m)
#pragma unroll
    for (int n = 0; n < 4; ++n) acc3[m][n] = (f32x4){0.f, 0.f, 0.f, 0.f};

#pragma unroll
  for (int kt = 0; kt < 8; ++kt) {
    const int cur = kt & 1;
    if (kt < 7) {
#pragma unroll
      for (int tt = 0; tt < 4; ++tt) {
        int nt = w * 4 + tt;
        bb3[cur ^ 1][tt] = ldfrag(pW2 + ((size_t)(nt * 8 + (kt + 1)) * 64 + l) * 8);
      }
    }
    bf16x8 afr[4];
#pragma unroll
    for (int m = 0; m < 4; ++m) {
      int row = m * 16 + l15;
      int byte = row * 512 + kt * 64 + lhi * 16;
      byte ^= ((row & 15) << 4);
      afr[m] = *reinterpret_cast<const bf16x8*>(B + byte);
    }
    __builtin_amdgcn_s_setprio(1);
#pragma unroll
    for (int tt = 0; tt < 4; ++tt)
#pragma unroll
      for (int m = 0; m < 4; ++m)
        acc3[m][tt] = __builtin_amdgcn_mfma_f32_16x16x32_bf16(afr[m], bb3[cur][tt], acc3[m][tt], 0, 0, 0);
    __builtin_amdgcn_s_setprio(0);
  }
  __syncthreads();   // B7: all r2 reads done -> B free for epilogue

  // ---- epilogue: two 32-row halves through B (fp32 [32][256] swz),
  // residual read coalesced from A (x bf16), nontemporal float4 stores.
#pragma unroll
  for (int hh = 0; hh < 2; ++hh) {
    if (hh) __syncthreads();   // half-0 reads done before overwrite
#pragma unroll
    for (int tt = 0; tt < 4; ++tt) {
      int colg = w * 64 + tt * 16 + l15;
#pragma unroll
      for (int mm = 0; mm < 2; ++mm) {
        int m = hh * 2 + mm;
#pragma unroll
        for (int reg = 0; reg < 4; ++reg) {
          int r = mm * 16 + lhi * 4 + reg;
          int byte = r * 1024 + colg * 4;
          byte ^= ((r & 15) << 4);
          *reinterpret_cast<float*>(B + byte) = acc3[m][tt][reg] + b2v[tt];
        }
      }
    }
    __syncthreads();
#pragma unroll
    for (int i = 0; i < 8; ++i) {
      int r = i * 4 + w;               // wave-uniform row within half
      int byte = r * 1024 + l * 16;
      byte ^= ((r & 15) << 4);
      f32x4 v = *reinterpret_cast<const f32x4*>(B + byte);
      int grow = hh * 32 + r;
      int xbyte = grow * 512 + l * 8;  // 4 bf16 of x
      xbyte ^= ((grow & 15) << 4);
      const ushort_t* xp = reinterpret_cast<const ushort_t*>(A + xbyte);
      v.x += bf2f(xp[0]); v.y += bf2f(xp[1]); v.z += bf2f(xp[2]); v.w += bf2f(xp[3]);
      f32x4* op = reinterpret_cast<f32x4*>(out + (size_t)(r0 + grow) * 256 + l * 4);
      __builtin_nontemporal_store(v, op);
    }
  }
}

extern "C" void kernel_launch(void* const* d_in, const int* in_sizes, int n_in,
                              void* d_out, int out_size, void* d_ws, size_t ws_size,
                              hipStream_t stream) {
  const float* x      = (const float*)d_in[0];
  const float* cond   = (const float*)d_in[1];
  const float* W_film = (const float*)d_in[2];
  const float* b_film = (const float*)d_in[3];
  const float* W1     = (const float*)d_in[4];
  const float* b1     = (const float*)d_in[5];
  const float* W2     = (const float*)d_in[6];
  const float* b2     = (const float*)d_in[7];
  float* out = (float*)d_out;

  ushort_t* p1  = (ushort_t*)d_ws;      // 512KB
  ushort_t* pW1 = p1 + 262144;          // 128KB
  ushort_t* pW2 = pW1 + 65536;          // 128KB

  hipLaunchKernelGGL(pack_weights, dim3(192), dim3(256), 0, stream,
                     W_film, W1, W2, p1, pW1, pW2);
  hipLaunchKernelGGL(film_fused, dim3(65536 / 64), dim3(256), 0, stream,
                     x, cond, b_film, b1, b2, p1, pW1, pW2, out);
}